// Round 12
// baseline (516.615 us; speedup 1.0000x reference)
//
#include <hip/hip_runtime.h>

// ---------------- problem constants ----------------
#define BB   512
#define SS   150
#define LL   50
#define DD   128
#define HH   8
#define DHH  16
#define FFD  256
#define NLL  2
#define MM   (SS*BB)          // 76800 rows
#define MDSZ ((size_t)MM*DD)  // 9830400 elements
#define QKVSTR ((size_t)512*384)   // qkv buffer row stride per s-step

typedef unsigned short u16;
typedef __attribute__((ext_vector_type(8))) short short8;   // 8 bf16 (4 VGPRs)
typedef __attribute__((ext_vector_type(4))) float f32x4;

__device__ __forceinline__ float bf2f(u16 u) {
    return __uint_as_float(((unsigned int)u) << 16);
}
__device__ __forceinline__ u16 f2bf(float f) {
    unsigned int x = __float_as_uint(f);
    unsigned int r = (x + 0x7fffu + ((x >> 16) & 1u)) >> 16;   // RNE
    return (u16)r;
}
__device__ __forceinline__ float ldv(const void* p, size_t i, int bf) {
    return bf ? bf2f(((const u16*)p)[i]) : ((const float*)p)[i];
}
__device__ __forceinline__ float rd_scalar(const void* p) {
    const u16* q = (const u16*)p;
    u16 lo = q[0];
    if (lo != 0) return bf2f(lo);
    return *(const float*)p;
}
__device__ __forceinline__ f32x4 mfma16(short8 a, short8 b, f32x4 c) {
    return __builtin_amdgcn_mfma_f32_16x16x32_bf16(a, b, c, 0, 0, 0);
}

// ---------------- dtype detect via ln1g[0] == 1.0 ----------------
__global__ void detect_kernel(const u16* __restrict__ ln1g, int* __restrict__ flag)
{
    *flag = (ln1g[0] == 0x3F80) ? 1 : 0;
}

// ---------------- weight prep ----------------
#define WOFF_IPW 0
#define WOFF_OPW 98304
#define WOFF_L1W 131072
#define WOFF_L2W 196608
#define WTOTAL   262144
__global__ __launch_bounds__(256) void prep_kernel(
    const void* __restrict__ ipw, const void* __restrict__ opw,
    const void* __restrict__ l1w, const void* __restrict__ l2w,
    u16* __restrict__ wbf, const int* __restrict__ flag)
{
    int bf = *flag;
    int idx = blockIdx.x * 256 + threadIdx.x;
    if (idx >= WTOTAL) return;
    const void* src; size_t i;
    if (idx < WOFF_OPW)      { src = ipw; i = idx; }
    else if (idx < WOFF_L1W) { src = opw; i = idx - WOFF_OPW; }
    else if (idx < WOFF_L2W) { src = l1w; i = idx - WOFF_L1W; }
    else                     { src = l2w; i = idx - WOFF_L2W; }
    wbf[idx] = bf ? ((const u16*)src)[i] : f2bf(((const float*)src)[i]);
}

// ---------------- embed ----------------
__global__ __launch_bounds__(256) void embed_kernel(
    const void* __restrict__ inputs, const void* __restrict__ emb_w,
    const void* __restrict__ emb_b, u16* __restrict__ x,
    const int* __restrict__ flag)
{
    int bf = *flag;
    size_t idx = (size_t)blockIdx.x * 256 + threadIdx.x;   // < MM*DD
    int d = (int)(idx & 127);
    int m = (int)(idx >> 7);
    int s = m >> 9;
    int b = m & 511;
    float pos = ldv(inputs, (size_t)(b * SS + s) * 4 + 0, bf);
    x[idx] = f2bf(pos * ldv(emb_w, d, bf) + ldv(emb_b, d, bf));
}

// ---------------- BARRIER-FREE MFMA bf16 GEMM ----------------
// C = A(MxK,bf16) * W(NxK,bf16)^T + bias. 64x128 tile, 4 waves 2x2, NO LDS for
// A/W: fragments loaded directly from global (row-major K-contig => short8 at
// row*K + ks + quad*8, 16-B aligned; W is L2-resident, reused by all m-blocks).
// Zero K-loop barriers -> compiler software-pipelines freely; occupancy is
// VGPR-bound (~6 waves/SIMD). Grid: x = m-block (1200 % 8 == 0 -> all n-blocks
// of one m-slab land on the same XCD: A lines fetched once).
// EPI: 0 = bias store, 1 = ReLU, 3 = residual + LayerNorm fused (N==128, grid.y==1)
template<int EPI, int KK>
__global__ __launch_bounds__(256) void mfma_gemm(
    const u16* __restrict__ A, const u16* __restrict__ W,
    const void* __restrict__ bias, size_t boff,
    void* __restrict__ out, const u16* __restrict__ resid,
    int N, const int* __restrict__ flag,
    const void* __restrict__ lng, const void* __restrict__ lnb, size_t goff)
{
    int bf = *flag;
    int tid  = threadIdx.x;
    int wave = tid >> 6, lane = tid & 63;
    int wy = wave >> 1, wx = wave & 1;          // wave: rows wy*32.., cols wx*64..
    int quad = lane >> 4, lr = lane & 15;
    int m0 = blockIdx.x * 64, n0 = blockIdx.y * 128;

    const u16* Abase = A + (size_t)(m0 + wy * 32 + lr) * KK + quad * 8;
    const u16* Wbase = W + (size_t)(n0 + wx * 64 + lr) * KK + quad * 8;

    f32x4 acc[2][4] = {};

#pragma unroll
    for (int ks = 0; ks < KK; ks += 32) {
        short8 a[2], b[4];
#pragma unroll
        for (int i = 0; i < 2; ++i)
            a[i] = *(const short8*)(Abase + (size_t)i * 16 * KK + ks);
#pragma unroll
        for (int j = 0; j < 4; ++j)
            b[j] = *(const short8*)(Wbase + (size_t)j * 16 * KK + ks);
#pragma unroll
        for (int i = 0; i < 2; ++i)
#pragma unroll
            for (int j = 0; j < 4; ++j)
                acc[i][j] = mfma16(a[i], b[j], acc[i][j]);
    }

    if (EPI == 3) {
        // ---- fused residual + LayerNorm (N == 128, n0 == 0) ----
        __shared__ float red[256];       // [wx][{s1,s2}][64 rows]
        float bvj[4];
#pragma unroll
        for (int j = 0; j < 4; ++j) bvj[j] = ldv(bias, boff + wx * 64 + j * 16 + lr, bf);

        float s1[2][4] = {}, s2[2][4] = {};
#pragma unroll
        for (int j = 0; j < 4; ++j) {
            int c = wx * 64 + j * 16 + lr;
#pragma unroll
            for (int i = 0; i < 2; ++i)
#pragma unroll
                for (int r = 0; r < 4; ++r) {
                    int m = m0 + wy * 32 + i * 16 + quad * 4 + r;
                    float v = acc[i][j][r] + bvj[j] +
                              bf2f(resid[(size_t)m * 128 + c]);
                    acc[i][j][r] = v;
                    s1[i][r] += v;
                    s2[i][r] += v * v;
                }
        }
#pragma unroll
        for (int i = 0; i < 2; ++i)
#pragma unroll
            for (int r = 0; r < 4; ++r)
#pragma unroll
                for (int msk = 1; msk < 16; msk <<= 1) {
                    s1[i][r] += __shfl_xor(s1[i][r], msk);
                    s2[i][r] += __shfl_xor(s2[i][r], msk);
                }

        if (lr == 0) {
#pragma unroll
            for (int i = 0; i < 2; ++i)
#pragma unroll
                for (int r = 0; r < 4; ++r) {
                    int row = wy * 32 + i * 16 + quad * 4 + r;
                    red[wx * 128 + row]      = s1[i][r];
                    red[wx * 128 + 64 + row] = s2[i][r];
                }
        }
        __syncthreads();

        float gj[4], bj[4];
#pragma unroll
        for (int j = 0; j < 4; ++j) {
            int c = wx * 64 + j * 16 + lr;
            gj[j] = ldv(lng, goff + c, bf);
            bj[j] = ldv(lnb, goff + c, bf);
        }
#pragma unroll
        for (int i = 0; i < 2; ++i)
#pragma unroll
            for (int r = 0; r < 4; ++r) {
                int row = wy * 32 + i * 16 + quad * 4 + r;
                float t1 = red[row] + red[128 + row];
                float t2 = red[64 + row] + red[192 + row];
                float mu = t1 * (1.f / 128.f);
                float rstd = rsqrtf(t2 * (1.f / 128.f) - mu * mu + 1e-5f);
                size_t m = (size_t)(m0 + row);
#pragma unroll
                for (int j = 0; j < 4; ++j) {
                    int c = wx * 64 + j * 16 + lr;
                    ((u16*)out)[m * 128 + c] =
                        f2bf((acc[i][j][r] - mu) * rstd * gj[j] + bj[j]);
                }
            }
        return;
    }

    // ---- EPI 0/1: direct bf16 store (L2 write-combining merges the tile) ----
#pragma unroll
    for (int j = 0; j < 4; ++j) {
        int c = n0 + wx * 64 + j * 16 + lr;
        float bvj = ldv(bias, boff + c, bf);
#pragma unroll
        for (int i = 0; i < 2; ++i) {
#pragma unroll
            for (int r = 0; r < 4; ++r) {
                int m = m0 + wy * 32 + i * 16 + quad * 4 + r;
                float v = acc[i][j][r] + bvj;
                if (EPI == 1) v = fmaxf(v, 0.f);
                ((u16*)out)[(size_t)m * N + c] = f2bf(v);
            }
        }
    }
}

// ---------------- MFMA flash attention (round-11, verified) ----------------
// QKV contiguous (M=s*512+b, 384): q [0,128), k [128,256), v [256,384).
// Pair decode: line-sharing head pairs (b,2j)/(b,2j+1) are blocks bid and bid+8:
// same XCD AND adjacent dispatch -> 64-B lines fetched once.
#define KSTR 24    // K_lds row stride (u16)
#define VSTR 168   // Vt_lds row stride
#define PSTR 168   // P_lds row stride

template<int I>
__device__ __forceinline__ void attn_tile(
    const u16* __restrict__ qbase, int b, int h,
    const u16* K_lds, const u16* Vt_lds, u16* P_lds,
    u16* __restrict__ o, int lr, int quad)
{
    const f32x4 zz = {0.f, 0.f, 0.f, 0.f};
    short8 qf = {};
    int qrow = 16 * I + lr; if (qrow > SS - 1) qrow = SS - 1;
    if (quad < 2) qf = *(const short8*)(qbase + (size_t)qrow * QKVSTR + quad * 8);

    f32x4 sc[I + 1];
#pragma unroll
    for (int jt = 0; jt <= I; ++jt) {
        short8 kf = *(const short8*)(K_lds + (16 * jt + lr) * KSTR + (quad & 1) * 8);
        sc[jt] = mfma16(qf, kf, zz);
    }

    float inv[4];
#pragma unroll
    for (int r = 0; r < 4; ++r) {
        int rg = 16 * I + quad * 4 + r;
        float mx = -3e38f;
#pragma unroll
        for (int jt = 0; jt <= I; ++jt) {
            int cg = 16 * jt + lr;
            float s = (cg <= rg) ? sc[jt][r] * 0.25f : -3e38f;
            sc[jt][r] = s;
            mx = fmaxf(mx, s);
        }
#pragma unroll
        for (int m = 1; m < 16; m <<= 1) mx = fmaxf(mx, __shfl_xor(mx, m));
        float sm = 0.f;
#pragma unroll
        for (int jt = 0; jt <= I; ++jt) {
            float p = (sc[jt][r] > -2e38f) ? __expf(sc[jt][r] - mx) : 0.f;
            sm += p;
            P_lds[(quad * 4 + r) * PSTR + 16 * jt + lr] = f2bf(p);
        }
        if ((I + 1) & 1)
            P_lds[(quad * 4 + r) * PSTR + 16 * (I + 1) + lr] = 0;
#pragma unroll
        for (int m = 1; m < 16; m <<= 1) sm += __shfl_xor(sm, m);
        inv[r] = 1.f / sm;
    }

    f32x4 oa = zz;
#pragma unroll
    for (int ch = 0; ch < (I + 2) / 2; ++ch) {
        short8 pf = *(const short8*)(P_lds + lr * PSTR + ch * 32 + quad * 8);
        short8 vf = *(const short8*)(Vt_lds + lr * VSTR + ch * 32 + quad * 8);
        oa = mfma16(pf, vf, oa);
    }
#pragma unroll
    for (int r = 0; r < 4; ++r) {
        int rg = 16 * I + quad * 4 + r;
        if (rg < SS)
            o[((size_t)rg * BB + b) * DD + h * DHH + lr] = f2bf(oa[r] * inv[r]);
    }
}

__global__ __launch_bounds__(320) void attn_kernel(
    const u16* __restrict__ qkv, u16* __restrict__ o)
{
    __shared__ __attribute__((aligned(16))) u16 K_lds[160 * KSTR];
    __shared__ __attribute__((aligned(16))) u16 Vt_lds[16 * VSTR];
    __shared__ __attribute__((aligned(16))) u16 P_lds[5 * 16 * PSTR];

    int bid = blockIdx.x;                      // pair-wise decode (see header)
    int hp = bid >> 10;
    int r  = bid & 1023;
    int parity = (r >> 3) & 1;
    int b = (r & 7) | ((r >> 4) << 3);
    int h = hp * 2 + parity;
    int tid = threadIdx.x;
    const u16* qbase = qkv + (size_t)b * 384 + h * 16;   // + s*QKVSTR per row

    u16* Vs = P_lds;   // V staging scratch (s-major, 160x16), reused by P later
    {   // K and V staging: row = s (0..159, zero-pad), 8 d-elements per half
        int row = tid >> 1, half = tid & 1;
        uint4 kv = {0u, 0u, 0u, 0u}, vv = {0u, 0u, 0u, 0u};
        if (row < SS) {
            const u16* p = qbase + (size_t)row * QKVSTR + half * 8;
            kv = *(const uint4*)(p + 128);
            vv = *(const uint4*)(p + 256);
        }
        *(uint4*)(K_lds + row * KSTR + half * 8) = kv;
        *(uint4*)(Vs + row * 16 + half * 8)      = vv;
    }
    __syncthreads();
    // transpose Vs(s,d) -> Vt(d,s)
    for (int idx = tid; idx < 16 * 160; idx += 320) {
        int d = idx & 15, s = idx >> 4;
        Vt_lds[d * VSTR + s] = Vs[s * 16 + d];
    }
    __syncthreads();

    int wv = tid >> 6, lane = tid & 63;
    int quad = lane >> 4, lr = lane & 15;
    u16* P = P_lds + wv * 16 * PSTR;

    switch (wv) {
    case 0: attn_tile<0>(qbase, b, h, K_lds, Vt_lds, P, o, lr, quad);
            attn_tile<9>(qbase, b, h, K_lds, Vt_lds, P, o, lr, quad); break;
    case 1: attn_tile<1>(qbase, b, h, K_lds, Vt_lds, P, o, lr, quad);
            attn_tile<8>(qbase, b, h, K_lds, Vt_lds, P, o, lr, quad); break;
    case 2: attn_tile<2>(qbase, b, h, K_lds, Vt_lds, P, o, lr, quad);
            attn_tile<7>(qbase, b, h, K_lds, Vt_lds, P, o, lr, quad); break;
    case 3: attn_tile<3>(qbase, b, h, K_lds, Vt_lds, P, o, lr, quad);
            attn_tile<6>(qbase, b, h, K_lds, Vt_lds, P, o, lr, quad); break;
    case 4: attn_tile<4>(qbase, b, h, K_lds, Vt_lds, P, o, lr, quad);
            attn_tile<5>(qbase, b, h, K_lds, Vt_lds, P, o, lr, quad); break;
    }
}

// ---------------- fused heads ----------------
__global__ __launch_bounds__(64) void head_kernel(
    const u16* __restrict__ x, const void* __restrict__ inputs,
    const void* __restrict__ his,
    const void* s0p, const void* Tp, const void* ap, const void* bp, const void* vdp,
    const void* __restrict__ dec_w, const void* dec_b,
    const void* fus_w, const void* fus_b,
    void* __restrict__ out, const int* __restrict__ flag)
{
    int bf = *flag;
    int b = blockIdx.x * 64 + threadIdx.x;
    if (b >= BB) return;

    const u16* enc = x + ((size_t)((SS - 1) * BB + b)) * DD;
    float dot = 0.f;
    for (int d = 0; d < DD; ++d) dot += bf2f(enc[d]) * ldv(dec_w, d, bf);
    float outv = dot + ldv(dec_b, 0, bf);

    float last = ldv(inputs, (size_t)(b * SS + (SS - 1)) * 4 + 0, bf);
    float prev = ldv(inputs, (size_t)(b * SS + (SS - 1 - LL)) * 4 + 0, bf);
    float dvh = (last - prev) * (1.f / (float)LL);

    float s0 = rd_scalar(s0p), T = rd_scalar(Tp), a = rd_scalar(ap);
    float bb = rd_scalar(bp), vd = rd_scalar(vdp);
    float sq = 2.f * sqrtf(a * bb);
    const float dt = 0.1f;

    auto v0compute = [&](int bi) {
        size_t ip = (size_t)(bi * SS + (SS - 1)) * 4;
        float v  = ldv(inputs, ip + 1, bf);
        float s  = ldv(inputs, ip + 2, bf);
        float dv = ldv(inputs, ip + 3, bf);
        float sx = s0 + fmaxf(0.f, v * T + v * dv / sq);
        float r = v / vd, r2 = r * r;
        float rs = sx / s;
        float af = a * (1.f - r2 * r2 - rs * rs);
        return fmaxf(v + af * dt, 0.f);
    };
    float v0_last = v0compute(BB - 1);   // reference bug: y0 uses v0[-1] for ALL batches
    float v0      = v0compute(b);
    float y0 = last + v0_last * dt;

    float fw0 = ldv(fus_w, 0, bf), fw1 = ldv(fus_w, 1, bf), fw2 = ldv(fus_w, 2, bf);
    float fb  = ldv(fus_b, 0, bf);

    auto store = [&](int idx, float val) {
        if (bf) ((u16*)out)[idx] = f2bf(val);
        else    ((float*)out)[idx] = val;
    };

    store(b * LL + 0, fw0 * outv + fw1 * (last + dvh * 1.f) + fw2 * y0 + fb);

    float vj = v0, yj = y0;
    for (int j = 0; j < LL - 1; ++j) {
        float hy = ldv(his, (size_t)(b * LL + j) * 2 + 0, bf);
        float hv = ldv(his, (size_t)(b * LL + j) * 2 + 1, bf);
        float dvj = hv - vj;
        float sj  = hy - yj;
        float sx = s0 + fmaxf(0.f, vj * T + vj * dvj / sq);
        float r = vj / vd, r2 = r * r;
        float rs = sx / sj;
        float acc = a * (1.f - r2 * r2 - rs * rs);
        float v2 = vj + acc * dt;
        v2 = (v2 <= 0.f) ? 0.f : v2;
        float y2 = yj + v2 * dt;
        int l = j + 1;
        float histl = last + dvh * (float)(l + 1);
        store(b * LL + l, fw0 * outv + fw1 * histl + fw2 * y2 + fb);
        vj = v2; yj = y2;
    }
}

// ---------------- launch ----------------
extern "C" void kernel_launch(void* const* d_in, const int* in_sizes, int n_in,
                              void* d_out, int out_size, void* d_ws, size_t ws_size,
                              hipStream_t stream)
{
    const void* inputs = d_in[0];
    const void* his    = d_in[1];
    const void* s0p    = d_in[2];
    const void* Tp     = d_in[3];
    const void* ap     = d_in[4];
    const void* bp     = d_in[5];
    const void* vdp    = d_in[6];
    const void* emb_w  = d_in[7];
    const void* emb_b  = d_in[8];
    const void* ipw    = d_in[9];
    const void* ipb    = d_in[10];
    const void* opw    = d_in[11];
    const void* opb    = d_in[12];
    const void* ln1g   = d_in[13];
    const void* ln1b   = d_in[14];
    const void* l1w    = d_in[15];
    const void* l1b    = d_in[16];
    const void* l2w    = d_in[17];
    const void* l2b    = d_in[18];
    const void* ln2g   = d_in[19];
    const void* ln2b   = d_in[20];
    const void* dec_w  = d_in[21];
    const void* dec_b  = d_in[22];
    const void* fus_w  = d_in[23];
    const void* fus_b  = d_in[24];

    // workspace layout (u16 units): 7*MDSZ + WTOTAL + flag ~= 138 MB
    u16*   wsu  = (u16*)d_ws;
    u16*   bx   = wsu;                   // x / LN outputs (M,D) bf16
    u16*   bqkv = wsu + 1 * MDSZ;        // qkv contiguous (M,384) bf16 (3*MDSZ)
    u16*   bo   = wsu + 4 * MDSZ;        // attn out (S,B,D) bf16
    u16*   h1   = wsu + 5 * MDSZ;        // relu(ff1) (M,FF) bf16 (2*MDSZ)
    u16*   wbf  = wsu + 7 * MDSZ;        // bf16 weights
    int*   flag = (int*)(wsu + 7 * MDSZ + WTOTAL);

    detect_kernel<<<1, 1, 0, stream>>>((const u16*)ln1g, flag);
    prep_kernel<<<(WTOTAL + 255) / 256, 256, 0, stream>>>(ipw, opw, l1w, l2w, wbf, flag);
    embed_kernel<<<(MM * DD) / 256, 256, 0, stream>>>(inputs, emb_w, emb_b, bx, flag);

    for (int l = 0; l < NLL; ++l) {
        // qkv: (M,384) = x @ ipw^T   [grid: x = m-blocks, y = n-blocks]
        mfma_gemm<0, 128><<<dim3(MM / 64, 3), 256, 0, stream>>>(
            bx, wbf + WOFF_IPW + (size_t)l * 384 * 128, ipb, (size_t)l * 384,
            bqkv, nullptr, 384, flag, nullptr, nullptr, 0);
        attn_kernel<<<BB * HH, 320, 0, stream>>>(bqkv, bo);
        // proj + residual + LN1 -> bx (in-place safe: per-thread read-then-write)
        mfma_gemm<3, 128><<<dim3(MM / 64, 1), 256, 0, stream>>>(
            bo, wbf + WOFF_OPW + (size_t)l * 128 * 128, opb, (size_t)l * 128,
            bx, bx, 128, flag, ln1g, ln1b, (size_t)l * 128);
        // ff1 + relu -> h1
        mfma_gemm<1, 128><<<dim3(MM / 64, 2), 256, 0, stream>>>(
            bx, wbf + WOFF_L1W + (size_t)l * 256 * 128, l1b, (size_t)l * 256,
            h1, nullptr, 256, flag, nullptr, nullptr, 0);
        // ff2 + residual + LN2 -> bx
        mfma_gemm<3, 256><<<dim3(MM / 64, 1), 256, 0, stream>>>(
            h1, wbf + WOFF_L2W + (size_t)l * 128 * 256, l2b, (size_t)l * 128,
            bx, bx, 128, flag, ln2g, ln2b, (size_t)l * 128);
    }

    head_kernel<<<BB / 64, 64, 0, stream>>>(
        bx, inputs, his, s0p, Tp, ap, bp, vdp,
        dec_w, dec_b, fus_w, fus_b, d_out, flag);

    (void)in_sizes; (void)n_in; (void)out_size; (void)ws_size;
}

// Round 13
// 386.506 us; speedup vs baseline: 1.3366x; 1.3366x over previous
//
#include <hip/hip_runtime.h>

// ---------------- problem constants ----------------
#define BB   512
#define SS   150
#define LL   50
#define DD   128
#define HH   8
#define DHH  16
#define FFD  256
#define NLL  2
#define MM   (SS*BB)          // 76800 rows
#define MDSZ ((size_t)MM*DD)  // 9830400 elements
#define QKVSTR ((size_t)512*384)   // qkv buffer row stride per s-step

typedef unsigned short u16;
typedef __attribute__((ext_vector_type(8))) short short8;   // 8 bf16 (4 VGPRs)
typedef __attribute__((ext_vector_type(4))) float f32x4;

__device__ __forceinline__ float bf2f(u16 u) {
    return __uint_as_float(((unsigned int)u) << 16);
}
__device__ __forceinline__ u16 f2bf(float f) {
    unsigned int x = __float_as_uint(f);
    unsigned int r = (x + 0x7fffu + ((x >> 16) & 1u)) >> 16;   // RNE
    return (u16)r;
}
__device__ __forceinline__ float ldv(const void* p, size_t i, int bf) {
    return bf ? bf2f(((const u16*)p)[i]) : ((const float*)p)[i];
}
__device__ __forceinline__ float rd_scalar(const void* p) {
    const u16* q = (const u16*)p;
    u16 lo = q[0];
    if (lo != 0) return bf2f(lo);
    return *(const float*)p;
}
__device__ __forceinline__ f32x4 mfma16(short8 a, short8 b, f32x4 c) {
    return __builtin_amdgcn_mfma_f32_16x16x32_bf16(a, b, c, 0, 0, 0);
}

// ---------------- dtype detect via ln1g[0] == 1.0 ----------------
__global__ void detect_kernel(const u16* __restrict__ ln1g, int* __restrict__ flag)
{
    *flag = (ln1g[0] == 0x3F80) ? 1 : 0;
}

// ---------------- weight prep ----------------
#define WOFF_IPW 0
#define WOFF_OPW 98304
#define WOFF_L1W 131072
#define WOFF_L2W 196608
#define WTOTAL   262144
__global__ __launch_bounds__(256) void prep_kernel(
    const void* __restrict__ ipw, const void* __restrict__ opw,
    const void* __restrict__ l1w, const void* __restrict__ l2w,
    u16* __restrict__ wbf, const int* __restrict__ flag)
{
    int bf = *flag;
    int idx = blockIdx.x * 256 + threadIdx.x;
    if (idx >= WTOTAL) return;
    const void* src; size_t i;
    if (idx < WOFF_OPW)      { src = ipw; i = idx; }
    else if (idx < WOFF_L1W) { src = opw; i = idx - WOFF_OPW; }
    else if (idx < WOFF_L2W) { src = l1w; i = idx - WOFF_L1W; }
    else                     { src = l2w; i = idx - WOFF_L2W; }
    wbf[idx] = bf ? ((const u16*)src)[i] : f2bf(((const float*)src)[i]);
}

// ---------------- embed ----------------
__global__ __launch_bounds__(256) void embed_kernel(
    const void* __restrict__ inputs, const void* __restrict__ emb_w,
    const void* __restrict__ emb_b, u16* __restrict__ x,
    const int* __restrict__ flag)
{
    int bf = *flag;
    size_t idx = (size_t)blockIdx.x * 256 + threadIdx.x;   // < MM*DD
    int d = (int)(idx & 127);
    int m = (int)(idx >> 7);
    int s = m >> 9;
    int b = m & 511;
    float pos = ldv(inputs, (size_t)(b * SS + s) * 4 + 0, bf);
    x[idx] = f2bf(pos * ldv(emb_w, d, bf) + ldv(emb_b, d, bf));
}

// ---------------- MFMA bf16 GEMM (round-9 structure, proven best) ----------------
// C = A(MxK,bf16) * W(NxK,bf16)^T + bias. 64x128 tile, BK=64, LDPK=72 (27 KB LDS,
// 5 blocks/CU), VGPR-staged coalesced global loads, direct epilogue stores
// (L2 write-combining merges the tile; LDS-staged stores measured NEUTRAL-NEGATIVE r11).
// Grid: x = m-block, y = n-block  (m-major linear ids; 1200 % 8 == 0 -> all n-blocks
// of one m-slab on the same XCD: A fetched once — measured FETCH 59->24 MB, r12).
// EPI: 0 = bias store, 1 = ReLU, 3 = residual + LayerNorm fused (N==128, grid.y==1)
#define LDPK 72
template<int EPI>
__global__ __launch_bounds__(256) void mfma_gemm(
    const u16* __restrict__ A, const u16* __restrict__ W,
    const void* __restrict__ bias, size_t boff,
    void* __restrict__ out, const u16* __restrict__ resid,
    int N, int K, const int* __restrict__ flag,
    const void* __restrict__ lng, const void* __restrict__ lnb, size_t goff)
{
    __shared__ __attribute__((aligned(16))) u16 As[64 * LDPK];
    __shared__ __attribute__((aligned(16))) u16 Bs[128 * LDPK];

    int bf = *flag;
    int tid  = threadIdx.x;
    int wave = tid >> 6, lane = tid & 63;
    int wy = wave >> 1, wx = wave & 1;          // wave: rows wy*32.., cols wx*64..
    int quad = lane >> 4, lr = lane & 15;
    int m0 = blockIdx.x * 64, n0 = blockIdx.y * 128;

    int aR = tid >> 2,          aC = (tid & 3) * 16;
    int bR0 = tid >> 2,         bC0 = (tid & 3) * 16;
    int bR1 = (tid + 256) >> 2, bC1 = (tid & 3) * 16;

    f32x4 acc[2][4] = {};

    for (int k0 = 0; k0 < K; k0 += 64) {
        const u16* ap  = A + (size_t)(m0 + aR) * K + k0 + aC;
        const u16* wp0 = W + (size_t)(n0 + bR0) * K + k0 + bC0;
        const u16* wp1 = W + (size_t)(n0 + bR1) * K + k0 + bC1;
        uint4 av0 = *(const uint4*)(ap);
        uint4 av1 = *(const uint4*)(ap + 8);
        uint4 w00 = *(const uint4*)(wp0);
        uint4 w01 = *(const uint4*)(wp0 + 8);
        uint4 w10 = *(const uint4*)(wp1);
        uint4 w11 = *(const uint4*)(wp1 + 8);
        __syncthreads();
        *(uint4*)(As + aR * LDPK + aC)       = av0;
        *(uint4*)(As + aR * LDPK + aC + 8)   = av1;
        *(uint4*)(Bs + bR0 * LDPK + bC0)     = w00;
        *(uint4*)(Bs + bR0 * LDPK + bC0 + 8) = w01;
        *(uint4*)(Bs + bR1 * LDPK + bC1)     = w10;
        *(uint4*)(Bs + bR1 * LDPK + bC1 + 8) = w11;
        __syncthreads();

#pragma unroll
        for (int ks = 0; ks < 64; ks += 32) {
            short8 a[2], b[4];
#pragma unroll
            for (int i = 0; i < 2; ++i)
                a[i] = *(const short8*)(As + (wy * 32 + i * 16 + lr) * LDPK + ks + quad * 8);
#pragma unroll
            for (int j = 0; j < 4; ++j)
                b[j] = *(const short8*)(Bs + (wx * 64 + j * 16 + lr) * LDPK + ks + quad * 8);
#pragma unroll
            for (int i = 0; i < 2; ++i)
#pragma unroll
                for (int j = 0; j < 4; ++j)
                    acc[i][j] = mfma16(a[i], b[j], acc[i][j]);
        }
    }

    if (EPI == 3) {
        // ---- fused residual + LayerNorm (N == 128, n0 == 0) ----
        float bvj[4];
#pragma unroll
        for (int j = 0; j < 4; ++j) bvj[j] = ldv(bias, boff + wx * 64 + j * 16 + lr, bf);

        float s1[2][4] = {}, s2[2][4] = {};
#pragma unroll
        for (int j = 0; j < 4; ++j) {
            int c = wx * 64 + j * 16 + lr;
#pragma unroll
            for (int i = 0; i < 2; ++i)
#pragma unroll
                for (int r = 0; r < 4; ++r) {
                    int m = m0 + wy * 32 + i * 16 + quad * 4 + r;
                    float v = acc[i][j][r] + bvj[j] +
                              bf2f(resid[(size_t)m * 128 + c]);
                    acc[i][j][r] = v;
                    s1[i][r] += v;
                    s2[i][r] += v * v;
                }
        }
#pragma unroll
        for (int i = 0; i < 2; ++i)
#pragma unroll
            for (int r = 0; r < 4; ++r)
#pragma unroll
                for (int msk = 1; msk < 16; msk <<= 1) {
                    s1[i][r] += __shfl_xor(s1[i][r], msk);
                    s2[i][r] += __shfl_xor(s2[i][r], msk);
                }

        __syncthreads();                 // all waves done with As (K-loop)
        float* red = (float*)As;         // [wx][{s1,s2}][64 rows] = 256 floats
        if (lr == 0) {
#pragma unroll
            for (int i = 0; i < 2; ++i)
#pragma unroll
                for (int r = 0; r < 4; ++r) {
                    int row = wy * 32 + i * 16 + quad * 4 + r;
                    red[wx * 128 + row]      = s1[i][r];
                    red[wx * 128 + 64 + row] = s2[i][r];
                }
        }
        __syncthreads();

        float gj[4], bj[4];
#pragma unroll
        for (int j = 0; j < 4; ++j) {
            int c = wx * 64 + j * 16 + lr;
            gj[j] = ldv(lng, goff + c, bf);
            bj[j] = ldv(lnb, goff + c, bf);
        }
#pragma unroll
        for (int i = 0; i < 2; ++i)
#pragma unroll
            for (int r = 0; r < 4; ++r) {
                int row = wy * 32 + i * 16 + quad * 4 + r;
                float t1 = red[row] + red[128 + row];
                float t2 = red[64 + row] + red[192 + row];
                float mu = t1 * (1.f / 128.f);
                float rstd = rsqrtf(t2 * (1.f / 128.f) - mu * mu + 1e-5f);
                size_t m = (size_t)(m0 + row);
#pragma unroll
                for (int j = 0; j < 4; ++j) {
                    int c = wx * 64 + j * 16 + lr;
                    ((u16*)out)[m * 128 + c] =
                        f2bf((acc[i][j][r] - mu) * rstd * gj[j] + bj[j]);
                }
            }
        return;
    }

    // ---- EPI 0/1: direct bf16 store ----
#pragma unroll
    for (int j = 0; j < 4; ++j) {
        int c = n0 + wx * 64 + j * 16 + lr;
        float bvj = ldv(bias, boff + c, bf);
#pragma unroll
        for (int i = 0; i < 2; ++i) {
#pragma unroll
            for (int r = 0; r < 4; ++r) {
                int m = m0 + wy * 32 + i * 16 + quad * 4 + r;
                float v = acc[i][j][r] + bvj;
                if (EPI == 1) v = fmaxf(v, 0.f);
                ((u16*)out)[(size_t)m * N + c] = f2bf(v);
            }
        }
    }
}

// ---------------- MFMA flash attention (round-11/12, verified) ----------------
// QKV contiguous (M=s*512+b, 384): q [0,128), k [128,256), v [256,384).
// Pair decode: line-sharing head pairs (b,2j)/(b,2j+1) are blocks bid and bid+8:
// same XCD AND adjacent dispatch -> 64-B lines fetched once (FETCH 80->50 MB, r11).
#define KSTR 24    // K_lds row stride (u16)
#define VSTR 168   // Vt_lds row stride
#define PSTR 168   // P_lds row stride

template<int I>
__device__ __forceinline__ void attn_tile(
    const u16* __restrict__ qbase, int b, int h,
    const u16* K_lds, const u16* Vt_lds, u16* P_lds,
    u16* __restrict__ o, int lr, int quad)
{
    const f32x4 zz = {0.f, 0.f, 0.f, 0.f};
    short8 qf = {};
    int qrow = 16 * I + lr; if (qrow > SS - 1) qrow = SS - 1;
    if (quad < 2) qf = *(const short8*)(qbase + (size_t)qrow * QKVSTR + quad * 8);

    f32x4 sc[I + 1];
#pragma unroll
    for (int jt = 0; jt <= I; ++jt) {
        short8 kf = *(const short8*)(K_lds + (16 * jt + lr) * KSTR + (quad & 1) * 8);
        sc[jt] = mfma16(qf, kf, zz);
    }

    float inv[4];
#pragma unroll
    for (int r = 0; r < 4; ++r) {
        int rg = 16 * I + quad * 4 + r;
        float mx = -3e38f;
#pragma unroll
        for (int jt = 0; jt <= I; ++jt) {
            int cg = 16 * jt + lr;
            float s = (cg <= rg) ? sc[jt][r] * 0.25f : -3e38f;
            sc[jt][r] = s;
            mx = fmaxf(mx, s);
        }
#pragma unroll
        for (int m = 1; m < 16; m <<= 1) mx = fmaxf(mx, __shfl_xor(mx, m));
        float sm = 0.f;
#pragma unroll
        for (int jt = 0; jt <= I; ++jt) {
            float p = (sc[jt][r] > -2e38f) ? __expf(sc[jt][r] - mx) : 0.f;
            sm += p;
            P_lds[(quad * 4 + r) * PSTR + 16 * jt + lr] = f2bf(p);
        }
        if ((I + 1) & 1)
            P_lds[(quad * 4 + r) * PSTR + 16 * (I + 1) + lr] = 0;
#pragma unroll
        for (int m = 1; m < 16; m <<= 1) sm += __shfl_xor(sm, m);
        inv[r] = 1.f / sm;
    }

    f32x4 oa = zz;
#pragma unroll
    for (int ch = 0; ch < (I + 2) / 2; ++ch) {
        short8 pf = *(const short8*)(P_lds + lr * PSTR + ch * 32 + quad * 8);
        short8 vf = *(const short8*)(Vt_lds + lr * VSTR + ch * 32 + quad * 8);
        oa = mfma16(pf, vf, oa);
    }
#pragma unroll
    for (int r = 0; r < 4; ++r) {
        int rg = 16 * I + quad * 4 + r;
        if (rg < SS)
            o[((size_t)rg * BB + b) * DD + h * DHH + lr] = f2bf(oa[r] * inv[r]);
    }
}

__global__ __launch_bounds__(320) void attn_kernel(
    const u16* __restrict__ qkv, u16* __restrict__ o)
{
    __shared__ __attribute__((aligned(16))) u16 K_lds[160 * KSTR];
    __shared__ __attribute__((aligned(16))) u16 Vt_lds[16 * VSTR];
    __shared__ __attribute__((aligned(16))) u16 P_lds[5 * 16 * PSTR];

    int bid = blockIdx.x;                      // pair-wise decode (see header)
    int hp = bid >> 10;
    int r  = bid & 1023;
    int parity = (r >> 3) & 1;
    int b = (r & 7) | ((r >> 4) << 3);
    int h = hp * 2 + parity;
    int tid = threadIdx.x;
    const u16* qbase = qkv + (size_t)b * 384 + h * 16;   // + s*QKVSTR per row

    u16* Vs = P_lds;   // V staging scratch (s-major, 160x16), reused by P later
    {   // K and V staging: row = s (0..159, zero-pad), 8 d-elements per half
        int row = tid >> 1, half = tid & 1;
        uint4 kv = {0u, 0u, 0u, 0u}, vv = {0u, 0u, 0u, 0u};
        if (row < SS) {
            const u16* p = qbase + (size_t)row * QKVSTR + half * 8;
            kv = *(const uint4*)(p + 128);
            vv = *(const uint4*)(p + 256);
        }
        *(uint4*)(K_lds + row * KSTR + half * 8) = kv;
        *(uint4*)(Vs + row * 16 + half * 8)      = vv;
    }
    __syncthreads();
    // transpose Vs(s,d) -> Vt(d,s)
    for (int idx = tid; idx < 16 * 160; idx += 320) {
        int d = idx & 15, s = idx >> 4;
        Vt_lds[d * VSTR + s] = Vs[s * 16 + d];
    }
    __syncthreads();

    int wv = tid >> 6, lane = tid & 63;
    int quad = lane >> 4, lr = lane & 15;
    u16* P = P_lds + wv * 16 * PSTR;

    switch (wv) {
    case 0: attn_tile<0>(qbase, b, h, K_lds, Vt_lds, P, o, lr, quad);
            attn_tile<9>(qbase, b, h, K_lds, Vt_lds, P, o, lr, quad); break;
    case 1: attn_tile<1>(qbase, b, h, K_lds, Vt_lds, P, o, lr, quad);
            attn_tile<8>(qbase, b, h, K_lds, Vt_lds, P, o, lr, quad); break;
    case 2: attn_tile<2>(qbase, b, h, K_lds, Vt_lds, P, o, lr, quad);
            attn_tile<7>(qbase, b, h, K_lds, Vt_lds, P, o, lr, quad); break;
    case 3: attn_tile<3>(qbase, b, h, K_lds, Vt_lds, P, o, lr, quad);
            attn_tile<6>(qbase, b, h, K_lds, Vt_lds, P, o, lr, quad); break;
    case 4: attn_tile<4>(qbase, b, h, K_lds, Vt_lds, P, o, lr, quad);
            attn_tile<5>(qbase, b, h, K_lds, Vt_lds, P, o, lr, quad); break;
    }
}

// ---------------- fused heads ----------------
__global__ __launch_bounds__(64) void head_kernel(
    const u16* __restrict__ x, const void* __restrict__ inputs,
    const void* __restrict__ his,
    const void* s0p, const void* Tp, const void* ap, const void* bp, const void* vdp,
    const void* __restrict__ dec_w, const void* dec_b,
    const void* fus_w, const void* fus_b,
    void* __restrict__ out, const int* __restrict__ flag)
{
    int bf = *flag;
    int b = blockIdx.x * 64 + threadIdx.x;
    if (b >= BB) return;

    const u16* enc = x + ((size_t)((SS - 1) * BB + b)) * DD;
    float dot = 0.f;
    for (int d = 0; d < DD; ++d) dot += bf2f(enc[d]) * ldv(dec_w, d, bf);
    float outv = dot + ldv(dec_b, 0, bf);

    float last = ldv(inputs, (size_t)(b * SS + (SS - 1)) * 4 + 0, bf);
    float prev = ldv(inputs, (size_t)(b * SS + (SS - 1 - LL)) * 4 + 0, bf);
    float dvh = (last - prev) * (1.f / (float)LL);

    float s0 = rd_scalar(s0p), T = rd_scalar(Tp), a = rd_scalar(ap);
    float bb = rd_scalar(bp), vd = rd_scalar(vdp);
    float sq = 2.f * sqrtf(a * bb);
    const float dt = 0.1f;

    auto v0compute = [&](int bi) {
        size_t ip = (size_t)(bi * SS + (SS - 1)) * 4;
        float v  = ldv(inputs, ip + 1, bf);
        float s  = ldv(inputs, ip + 2, bf);
        float dv = ldv(inputs, ip + 3, bf);
        float sx = s0 + fmaxf(0.f, v * T + v * dv / sq);
        float r = v / vd, r2 = r * r;
        float rs = sx / s;
        float af = a * (1.f - r2 * r2 - rs * rs);
        return fmaxf(v + af * dt, 0.f);
    };
    float v0_last = v0compute(BB - 1);   // reference bug: y0 uses v0[-1] for ALL batches
    float v0      = v0compute(b);
    float y0 = last + v0_last * dt;

    float fw0 = ldv(fus_w, 0, bf), fw1 = ldv(fus_w, 1, bf), fw2 = ldv(fus_w, 2, bf);
    float fb  = ldv(fus_b, 0, bf);

    auto store = [&](int idx, float val) {
        if (bf) ((u16*)out)[idx] = f2bf(val);
        else    ((float*)out)[idx] = val;
    };

    store(b * LL + 0, fw0 * outv + fw1 * (last + dvh * 1.f) + fw2 * y0 + fb);

    float vj = v0, yj = y0;
    for (int j = 0; j < LL - 1; ++j) {
        float hy = ldv(his, (size_t)(b * LL + j) * 2 + 0, bf);
        float hv = ldv(his, (size_t)(b * LL + j) * 2 + 1, bf);
        float dvj = hv - vj;
        float sj  = hy - yj;
        float sx = s0 + fmaxf(0.f, vj * T + vj * dvj / sq);
        float r = vj / vd, r2 = r * r;
        float rs = sx / sj;
        float acc = a * (1.f - r2 * r2 - rs * rs);
        float v2 = vj + acc * dt;
        v2 = (v2 <= 0.f) ? 0.f : v2;
        float y2 = yj + v2 * dt;
        int l = j + 1;
        float histl = last + dvh * (float)(l + 1);
        store(b * LL + l, fw0 * outv + fw1 * histl + fw2 * y2 + fb);
        vj = v2; yj = y2;
    }
}

// ---------------- launch ----------------
extern "C" void kernel_launch(void* const* d_in, const int* in_sizes, int n_in,
                              void* d_out, int out_size, void* d_ws, size_t ws_size,
                              hipStream_t stream)
{
    const void* inputs = d_in[0];
    const void* his    = d_in[1];
    const void* s0p    = d_in[2];
    const void* Tp     = d_in[3];
    const void* ap     = d_in[4];
    const void* bp     = d_in[5];
    const void* vdp    = d_in[6];
    const void* emb_w  = d_in[7];
    const void* emb_b  = d_in[8];
    const void* ipw    = d_in[9];
    const void* ipb    = d_in[10];
    const void* opw    = d_in[11];
    const void* opb    = d_in[12];
    const void* ln1g   = d_in[13];
    const void* ln1b   = d_in[14];
    const void* l1w    = d_in[15];
    const void* l1b    = d_in[16];
    const void* l2w    = d_in[17];
    const void* l2b    = d_in[18];
    const void* ln2g   = d_in[19];
    const void* ln2b   = d_in[20];
    const void* dec_w  = d_in[21];
    const void* dec_b  = d_in[22];
    const void* fus_w  = d_in[23];
    const void* fus_b  = d_in[24];

    // workspace layout (u16 units): 7*MDSZ + WTOTAL + flag ~= 138 MB
    u16*   wsu  = (u16*)d_ws;
    u16*   bx   = wsu;                   // x / LN outputs (M,D) bf16
    u16*   bqkv = wsu + 1 * MDSZ;        // qkv contiguous (M,384) bf16 (3*MDSZ)
    u16*   bo   = wsu + 4 * MDSZ;        // attn out (S,B,D) bf16
    u16*   h1   = wsu + 5 * MDSZ;        // relu(ff1) (M,FF) bf16 (2*MDSZ)
    u16*   wbf  = wsu + 7 * MDSZ;        // bf16 weights
    int*   flag = (int*)(wsu + 7 * MDSZ + WTOTAL);

    detect_kernel<<<1, 1, 0, stream>>>((const u16*)ln1g, flag);
    prep_kernel<<<(WTOTAL + 255) / 256, 256, 0, stream>>>(ipw, opw, l1w, l2w, wbf, flag);
    embed_kernel<<<(MM * DD) / 256, 256, 0, stream>>>(inputs, emb_w, emb_b, bx, flag);

    for (int l = 0; l < NLL; ++l) {
        // qkv: (M,384) = x @ ipw^T   [grid: x = m-blocks (m-major), y = n-blocks]
        mfma_gemm<0><<<dim3(MM / 64, 3), 256, 0, stream>>>(
            bx, wbf + WOFF_IPW + (size_t)l * 384 * 128, ipb, (size_t)l * 384,
            bqkv, nullptr, 384, 128, flag, nullptr, nullptr, 0);
        attn_kernel<<<BB * HH, 320, 0, stream>>>(bqkv, bo);
        // proj + residual + LN1 -> bx (in-place safe)
        mfma_gemm<3><<<dim3(MM / 64, 1), 256, 0, stream>>>(
            bo, wbf + WOFF_OPW + (size_t)l * 128 * 128, opb, (size_t)l * 128,
            bx, bx, 128, 128, flag, ln1g, ln1b, (size_t)l * 128);
        // ff1 + relu -> h1
        mfma_gemm<1><<<dim3(MM / 64, 2), 256, 0, stream>>>(
            bx, wbf + WOFF_L1W + (size_t)l * 256 * 128, l1b, (size_t)l * 256,
            h1, nullptr, 256, 128, flag, nullptr, nullptr, 0);
        // ff2 + residual + LN2 -> bx
        mfma_gemm<3><<<dim3(MM / 64, 1), 256, 0, stream>>>(
            h1, wbf + WOFF_L2W + (size_t)l * 128 * 256, l2b, (size_t)l * 128,
            bx, bx, 128, 256, flag, ln2g, ln2b, (size_t)l * 128);
    }

    head_kernel<<<BB / 64, 64, 0, stream>>>(
        bx, inputs, his, s0p, Tp, ap, bp, vdp,
        dec_w, dec_b, fus_w, fus_b, d_out, flag);

    (void)in_sizes; (void)n_in; (void)out_size; (void)ws_size;
}